// Round 21
// baseline (994.990 us; speedup 1.0000x reference)
//
#include <hip/hip_runtime.h>
#include <hip/hip_bf16.h>

#define NN 50000
#define EE 500000
#define RR 100
#define DD 32
#define LL 6
#define BB 4
#define KK 33
#define BD 128      // B*D
#define XDIM 416    // 13*D
#define NROWS (NN * BB)
#define FEPS 1e-6f
#define SCAN_B 1024
#define FB 16       // nodes per fused block (50000 = 3125 * 16)
#define FR 64       // rows per fused block
#define FSTR 132    // LDS row stride (128 + 4 pad)
#define RELSZ (2 * RR * BB * DD)

typedef __hip_bfloat16 bf16;
typedef unsigned short u16;
typedef __attribute__((ext_vector_type(2))) float f32x2;

__device__ __forceinline__ float b2f(bf16 x) { return __bfloat162float(x); }
__device__ __forceinline__ float bfu2f(u16 u) { return __uint_as_float((unsigned)u << 16); }
__device__ __forceinline__ u16 f2bfu(float f) {   // RNE
    unsigned u = __float_as_uint(f);
    return (u16)((u + 0x7FFFu + ((u >> 16) & 1u)) >> 16);
}
__device__ __forceinline__ float4 bf4(ushort4 u) {
    return make_float4(bfu2f(u.x), bfu2f(u.y), bfu2f(u.z), bfu2f(u.w));
}

// ---------- input dtype detection ----------
__global__ void k_detect(const void* q, int* flag) {
    if (threadIdx.x == 0 && blockIdx.x == 0) {
        const unsigned short* u = (const unsigned short*)q;
        int wild = 0;
        for (int i = 0; i < 256; i++) {
            int expo = (u[i] >> 7) & 0xFF;
            if (expo >= 134) wild++;   // |bf16| >= 128 (incl inf/nan)
        }
        *flag = (wild > 8) ? 1 : 0;
    }
}

__global__ void k_conv(const void* __restrict__ src, float* __restrict__ dst, int n,
                       const int* __restrict__ flag) {
    int i = blockIdx.x * 256 + threadIdx.x;
    if (i < n) {
        if (*flag) dst[i] = ((const float*)src)[i];
        else       dst[i] = b2f(((const bf16*)src)[i]);
    }
}

// ---------- graph preprocessing ----------
__global__ void k_degree(const int* __restrict__ el, int* __restrict__ cnt) {
    int e = blockIdx.x * blockDim.x + threadIdx.x;
    if (e < EE) atomicAdd(&cnt[el[e * 3 + 1]], 1);
}

__global__ void k_scan1(const int* __restrict__ cnt, int* __restrict__ incl, int* __restrict__ part) {
    __shared__ int sd[SCAN_B];
    int tid = threadIdx.x;
    int i = blockIdx.x * SCAN_B + tid;
    int v = (i < NN) ? cnt[i] : 0;
    sd[tid] = v;
    __syncthreads();
    for (int off = 1; off < SCAN_B; off <<= 1) {
        int t = (tid >= off) ? sd[tid - off] : 0;
        __syncthreads();
        sd[tid] += t;
        __syncthreads();
    }
    if (i < NN) incl[i] = sd[tid];
    if (tid == SCAN_B - 1) part[blockIdx.x] = sd[tid];
}

__global__ void k_scan2(int* part, int nb) {
    if (threadIdx.x == 0 && blockIdx.x == 0) {
        int run = 0;
        for (int i = 0; i < nb; i++) { int t = part[i]; part[i] = run; run += t; }
    }
}

__global__ void k_scan3(const int* __restrict__ incl, const int* __restrict__ part, int* __restrict__ row_ptr) {
    int i = blockIdx.x * blockDim.x + threadIdx.x;
    if (i < NN) row_ptr[i + 1] = incl[i] + part[i / SCAN_B];
    if (i == 0) row_ptr[0] = 0;
}

__global__ void k_scatter(const int* __restrict__ el, const int* __restrict__ row_ptr,
                          int* __restrict__ cur, int2* __restrict__ csr) {
    int e = blockIdx.x * blockDim.x + threadIdx.x;
    if (e < EE) {
        int dst = el[e * 3 + 1];
        int pos = row_ptr[dst] + atomicAdd(&cur[dst], 1);
        csr[pos] = make_int2(el[e * 3 + 0], el[e * 3 + 2]);
    }
}

__global__ void k_scale_sum(const int* __restrict__ cnt, float* __restrict__ ssum) {
    __shared__ float sd[256];
    int i = blockIdx.x * 256 + threadIdx.x;
    float v = (i < NN) ? logf((float)(cnt[i] + 1)) : 0.f;
    sd[threadIdx.x] = v;
    __syncthreads();
    for (int off = 128; off; off >>= 1) {
        if (threadIdx.x < off) sd[threadIdx.x] += sd[threadIdx.x + off];
        __syncthreads();
    }
    if (threadIdx.x == 0) atomicAdd(ssum, sd[0]);
}

__global__ void k_scale_fin(const int* __restrict__ cnt, const float* __restrict__ ssum,
                            float2* __restrict__ scales) {
    int i = blockIdx.x * 256 + threadIdx.x;
    if (i < NN) {
        float mean = *ssum / (float)NN;
        float s = logf((float)(cnt[i] + 1)) / mean;
        scales[i] = make_float2(s, 1.f / fmaxf(s, 0.01f));
    }
}

// ---------- query prep ----------
__global__ void k_prep(const int* __restrict__ h_index, const int* __restrict__ t_index,
                       const int* __restrict__ r_index, const float* __restrict__ query_emb,
                       int* __restrict__ h0, int* __restrict__ t_sel,
                       float* __restrict__ query) {
    __shared__ int s_h0[BB], s_r0[BB], s_neg[BB];
    int tid = threadIdx.x;
    if (tid < BB) {
        int h00 = h_index[tid * KK];
        int alleq = 1;
        for (int k = 1; k < KK; k++) alleq &= (h_index[tid * KK + k] == h00) ? 1 : 0;
        s_neg[tid] = alleq;
        s_h0[tid] = alleq ? h00 : t_index[tid * KK];
        s_r0[tid] = alleq ? r_index[tid * KK] : r_index[tid * KK] + RR;
        h0[tid] = s_h0[tid];
    }
    __syncthreads();
    for (int i = tid; i < BB * KK; i += blockDim.x) {
        int b = i / KK;
        t_sel[i] = s_neg[b] ? t_index[i] : h_index[i];
    }
    for (int i = tid; i < BB * DD; i += blockDim.x) {
        int b = i / DD, d = i - b * DD;
        query[i] = query_emb[s_r0[b] * DD + d];
    }
}

// ---------- rel_emb for ALL layers in one launch ----------
__global__ void k_rel_emb_all(const float* __restrict__ query, const float* __restrict__ relW,
                              const float* __restrict__ relb, float* __restrict__ rel_emb) {
    int gi = blockIdx.x * 256 + threadIdx.x;   // over LL * 2R*B*D
    if (gi >= LL * RELSZ) return;
    int l = gi / RELSZ;
    int i = gi - l * RELSZ;
    int r = i / BD;
    int bd = i - r * BD;
    int b = bd >> 5, d = bd & 31;
    const float* relWl = relW + (size_t)l * DD * 2 * RR * DD;
    const float* relbl = relb + (size_t)l * 2 * RR * DD;
    float acc = relbl[r * DD + d];
    #pragma unroll 8
    for (int k = 0; k < DD; k++)
        acc += query[b * DD + k] * relWl[k * (2 * RR * DD) + r * DD + d];
    rel_emb[gi] = acc;
}

// Reorganize lin_W into [V (384 rows = k*3+p) | Wh (32 rows)] x 32 cols per layer.
__global__ void k_reorg(const float* __restrict__ linWf, float* __restrict__ Wre) {
    int i = blockIdx.x * 256 + threadIdx.x;
    if (i >= LL * XDIM * DD) return;
    int l = i / (XDIM * DD);
    int rem = i - l * (XDIM * DD);
    int r = rem >> 5, c = rem & 31;
    int src;
    if (r < 384) {
        int k = r / 3, p = r - k * 3;
        int d = k & 31, s = k >> 5;
        src = 32 + d * 12 + s * 3 + p;
    } else {
        src = r - 384;
    }
    Wre[i] = linWf[(size_t)l * XDIM * DD + src * 32 + c];
}

#define EDGE_ACC(h4, r4)                                                          \
    {                                                                             \
        float v0 = h4.x * r4.x, v1 = h4.y * r4.y, v2 = h4.z * r4.z, v3 = h4.w * r4.w; \
        s0 += v0; s1 += v1; s2 += v2; s3 += v3;                                   \
        q0 += v0 * v0; q1 += v1 * v1; q2 += v2 * v2; q3 += v3 * v3;               \
        mx0 = fmaxf(mx0, v0); mx1 = fmaxf(mx1, v1); mx2 = fmaxf(mx2, v2); mx3 = fmaxf(mx3, v3); \
        mn0 = fminf(mn0, v0); mn1 = fminf(mn1, v1); mn2 = fminf(mn2, v2); mn3 = fminf(mn3, v3); \
    }

// Fused layer: hidden stored in bf16 (compute fp32). 16 nodes / 512 threads.
// Phase A: gather (8B ushort4 loads, x4 unroll) -> stats -> LDS.
// Phase B: k-loop loads x as float4 (ds_read_b128, conflict-free as r14-19),
//          then 6 v_pk_fma_f32 per k (same IEEE ops+order -> bit-identical);
//          W stays SGPR-resident via wave-uniform addressing.
__global__ __launch_bounds__(512, 8) void k_fused(
    const int* __restrict__ row_ptr, const int2* __restrict__ csr,
    const float2* __restrict__ scales, const float* __restrict__ query,
    const int* __restrict__ h0v, const float* __restrict__ rel_emb,
    const u16* __restrict__ hin, u16* __restrict__ hout,
    const float* __restrict__ Wre, const float* __restrict__ lbl, int l0) {
    __shared__ float sx[FR * FSTR];
    int tid = threadIdx.x;
    int nb0 = blockIdx.x * FB;
    const float4 zf4 = make_float4(0.f, 0.f, 0.f, 0.f);

    // ---- Phase A: stats into LDS (one round, 16 node-groups) ----
    {
        int ni = tid >> 5;
        int n = nb0 + ni;
        int t = tid & 31;
        int b = t >> 3;
        int dq = t & 7;
        int boff = b * DD + dq * 4;
        int h0b = h0v[b];
        float4 qv = *(const float4*)&query[boff];

        float4 bv = (h0b == n) ? qv : zf4;
        float s0 = bv.x, s1 = bv.y, s2 = bv.z, s3 = bv.w;
        float q0 = bv.x * bv.x, q1 = bv.y * bv.y, q2 = bv.z * bv.z, q3 = bv.w * bv.w;
        float mx0 = bv.x, mx1 = bv.y, mx2 = bv.z, mx3 = bv.w;
        float mn0 = bv.x, mn1 = bv.y, mn2 = bv.z, mn3 = bv.w;

        int e0 = row_ptr[n], e1 = row_ptr[n + 1];
        int e = e0;
        if (l0) {
            for (; e + 2 <= e1; e += 2) {
                int2 sa = csr[e];
                int2 sb = csr[e + 1];
                float4 ra = *(const float4*)&rel_emb[(size_t)sa.y * BD + boff];
                float4 rb = *(const float4*)&rel_emb[(size_t)sb.y * BD + boff];
                float4 ha = (sa.x == h0b) ? qv : zf4;
                float4 hb = (sb.x == h0b) ? qv : zf4;
                EDGE_ACC(ha, ra);
                EDGE_ACC(hb, rb);
            }
            if (e < e1) {
                int2 sr = csr[e];
                float4 r4 = *(const float4*)&rel_emb[(size_t)sr.y * BD + boff];
                float4 h4 = (sr.x == h0b) ? qv : zf4;
                EDGE_ACC(h4, r4);
            }
        } else {
            for (; e + 4 <= e1; e += 4) {
                int2 sa = csr[e];
                int2 sb = csr[e + 1];
                int2 sc2 = csr[e + 2];
                int2 sd2 = csr[e + 3];
                ushort4 hau = *(const ushort4*)&hin[(size_t)sa.x * BD + boff];
                float4 ra = *(const float4*)&rel_emb[(size_t)sa.y * BD + boff];
                ushort4 hbu = *(const ushort4*)&hin[(size_t)sb.x * BD + boff];
                float4 rb = *(const float4*)&rel_emb[(size_t)sb.y * BD + boff];
                ushort4 hcu = *(const ushort4*)&hin[(size_t)sc2.x * BD + boff];
                float4 rc = *(const float4*)&rel_emb[(size_t)sc2.y * BD + boff];
                ushort4 hdu = *(const ushort4*)&hin[(size_t)sd2.x * BD + boff];
                float4 rd = *(const float4*)&rel_emb[(size_t)sd2.y * BD + boff];
                float4 ha = bf4(hau), hb = bf4(hbu), hc = bf4(hcu), hd = bf4(hdu);
                EDGE_ACC(ha, ra);
                EDGE_ACC(hb, rb);
                EDGE_ACC(hc, rc);
                EDGE_ACC(hd, rd);
            }
            for (; e + 2 <= e1; e += 2) {
                int2 sa = csr[e];
                int2 sb = csr[e + 1];
                ushort4 hau = *(const ushort4*)&hin[(size_t)sa.x * BD + boff];
                float4 ra = *(const float4*)&rel_emb[(size_t)sa.y * BD + boff];
                ushort4 hbu = *(const ushort4*)&hin[(size_t)sb.x * BD + boff];
                float4 rb = *(const float4*)&rel_emb[(size_t)sb.y * BD + boff];
                float4 ha = bf4(hau), hb = bf4(hbu);
                EDGE_ACC(ha, ra);
                EDGE_ACC(hb, rb);
            }
            if (e < e1) {
                int2 sr = csr[e];
                ushort4 hu = *(const ushort4*)&hin[(size_t)sr.x * BD + boff];
                float4 r4 = *(const float4*)&rel_emb[(size_t)sr.y * BD + boff];
                float4 h4 = bf4(hu);
                EDGE_ACC(h4, r4);
            }
        }
        float cinv = 1.f / (float)(e1 - e0 + 1);
        float me0 = s0 * cinv, me1 = s1 * cinv, me2 = s2 * cinv, me3 = s3 * cinv;
        float sd0 = sqrtf(fmaxf(q0 * cinv - me0 * me0, FEPS));
        float sd1 = sqrtf(fmaxf(q1 * cinv - me1 * me1, FEPS));
        float sd2 = sqrtf(fmaxf(q2 * cinv - me2 * me2, FEPS));
        float sd3 = sqrtf(fmaxf(q3 * cinv - me3 * me3, FEPS));

        int d0 = dq * 4;
        float* dst = &sx[(ni * BB + b) * FSTR];
        *(float4*)&dst[0 * 32 + d0] = make_float4(me0, me1, me2, me3);
        *(float4*)&dst[1 * 32 + d0] = make_float4(mx0, mx1, mx2, mx3);
        *(float4*)&dst[2 * 32 + d0] = make_float4(mn0, mn1, mn2, mn3);
        *(float4*)&dst[3 * 32 + d0] = make_float4(sd0, sd1, sd2, sd3);
    }
    __syncthreads();

    // ---- Phase B: matvec (8 waves x 4 cols each), packed-f32 pairs ----
    int lr = tid & (FR - 1);
    int c0 = __builtin_amdgcn_readfirstlane((tid >> 6) << 2);  // wave-uniform col base
    int grow = blockIdx.x * FR + lr;
    float2 sc = scales[grow >> 2];
    const float* __restrict__ Wv = Wre;            // 384*32
    const float* __restrict__ Wh = Wre + 384 * 32;

    f32x2 A00 = {lbl[c0 + 0], lbl[c0 + 1]};
    f32x2 A01 = {lbl[c0 + 2], lbl[c0 + 3]};
    f32x2 A10 = {0.f, 0.f}, A11 = {0.f, 0.f};
    f32x2 A20 = {0.f, 0.f}, A21 = {0.f, 0.f};

    const float* xr = &sx[lr * FSTR];
    #pragma unroll 2
    for (int k4 = 0; k4 < 128; k4 += 4) {
        float4 x4 = *(const float4*)&xr[k4];   // ds_read_b128, conflict-free
        float xs[4] = {x4.x, x4.y, x4.z, x4.w};
        #pragma unroll
        for (int j = 0; j < 4; j++) {
            float x = xs[j];
            f32x2 xx = {x, x};
            const float* w = &Wv[(size_t)(k4 + j) * 96 + c0];
            f32x2 w00 = {w[0], w[1]};
            f32x2 w01 = {w[2], w[3]};
            f32x2 w10 = {w[32], w[33]};
            f32x2 w11 = {w[34], w[35]};
            f32x2 w20 = {w[64], w[65]};
            f32x2 w21 = {w[66], w[67]};
            asm("v_pk_fma_f32 %0, %1, %2, %0" : "+v"(A00) : "v"(xx), "s"(w00));
            asm("v_pk_fma_f32 %0, %1, %2, %0" : "+v"(A01) : "v"(xx), "s"(w01));
            asm("v_pk_fma_f32 %0, %1, %2, %0" : "+v"(A10) : "v"(xx), "s"(w10));
            asm("v_pk_fma_f32 %0, %1, %2, %0" : "+v"(A11) : "v"(xx), "s"(w11));
            asm("v_pk_fma_f32 %0, %1, %2, %0" : "+v"(A20) : "v"(xx), "s"(w20));
            asm("v_pk_fma_f32 %0, %1, %2, %0" : "+v"(A21) : "v"(xx), "s"(w21));
        }
    }
    float a0[4] = {A00[0], A00[1], A01[0], A01[1]};
    float a1[4] = {A10[0], A10[1], A11[0], A11[1]};
    float a2[4] = {A20[0], A20[1], A21[0], A21[1]};

    // hself: k2 ascending 0..31 (scalar, unchanged)
    if (l0) {
        int nB = grow >> 2, bB = grow & 3;
        bool selfq = (h0v[bB] == nB);
        const float* qrow = &query[bB * DD];
        #pragma unroll
        for (int q = 0; q < 8; q++) {
            float4 h4 = selfq ? *(const float4*)&qrow[q * 4] : zf4;
            float hx[4] = {h4.x, h4.y, h4.z, h4.w};
            #pragma unroll
            for (int j = 0; j < 4; j++) {
                const float* wh = &Wh[(size_t)(q * 4 + j) * 32 + c0];
                float x = hx[j];
                #pragma unroll
                for (int c = 0; c < 4; c++) a0[c] = fmaf(x, wh[c], a0[c]);
            }
        }
    } else {
        const unsigned* hrow32 = (const unsigned*)&hin[(size_t)grow * 32];
        #pragma unroll
        for (int q4 = 0; q4 < 4; q4++) {
            uint4 r4 = *(const uint4*)&hrow32[q4 * 4];
            unsigned uu[4] = {r4.x, r4.y, r4.z, r4.w};
            #pragma unroll
            for (int m = 0; m < 4; m++) {
                float xlo = __uint_as_float(uu[m] << 16);
                float xhi = __uint_as_float(uu[m] & 0xFFFF0000u);
                int kb = q4 * 8 + m * 2;
                const float* whl = &Wh[(size_t)kb * 32 + c0];
                const float* whh = &Wh[(size_t)(kb + 1) * 32 + c0];
                #pragma unroll
                for (int c = 0; c < 4; c++) a0[c] = fmaf(xlo, whl[c], a0[c]);
                #pragma unroll
                for (int c = 0; c < 4; c++) a0[c] = fmaf(xhi, whh[c], a0[c]);
            }
        }
    }

    float4 y;
    y.x = fmaxf(a0[0] + sc.x * a1[0] + sc.y * a2[0], 0.f);
    y.y = fmaxf(a0[1] + sc.x * a1[1] + sc.y * a2[1], 0.f);
    y.z = fmaxf(a0[2] + sc.x * a1[2] + sc.y * a2[2], 0.f);
    y.w = fmaxf(a0[3] + sc.x * a1[3] + sc.y * a2[3], 0.f);
    ushort4 yo;
    yo.x = f2bfu(y.x); yo.y = f2bfu(y.y); yo.z = f2bfu(y.z); yo.w = f2bfu(y.w);
    *(ushort4*)&hout[(size_t)grow * 32 + c0] = yo;
}

// ---------- scoring ----------
__global__ void k_score(const u16* __restrict__ hidden, const float* __restrict__ query,
                        const int* __restrict__ t_sel,
                        const float* __restrict__ W1, const float* __restrict__ b1,
                        const float* __restrict__ W2, const float* __restrict__ b2v,
                        void* __restrict__ out, const int* __restrict__ flag) {
    int bk = blockIdx.x;
    int b = bk / KK;
    int j = threadIdx.x;  // 0..63
    int t = t_sel[bk];
    __shared__ float feat[2 * DD];
    feat[j] = (j < DD) ? bfu2f(hidden[(size_t)t * BD + b * DD + j]) : query[b * DD + (j - DD)];
    __syncthreads();
    float acc = b1[j];
    #pragma unroll 8
    for (int i = 0; i < 2 * DD; i++) acc += feat[i] * W1[i * 2 * DD + j];
    float h = fmaxf(acc, 0.f);
    float c = h * W2[j];
    for (int off = 32; off; off >>= 1) c += __shfl_down(c, off);
    if (j == 0) {
        float r = c + b2v[0];
        if (*flag) ((float*)out)[bk] = r;
        else       ((bf16*)out)[bk] = __float2bfloat16(r);
    }
}

extern "C" void kernel_launch(void* const* d_in, const int* in_sizes, int n_in,
                              void* d_out, int out_size, void* d_ws, size_t ws_size,
                              hipStream_t stream) {
    const int* el = (const int*)d_in[0];
    const int* h_index = (const int*)d_in[1];
    const int* t_index = (const int*)d_in[2];
    const int* r_index = (const int*)d_in[3];

    char* ws = (char*)d_ws;
    size_t off = 0;
    auto alloc = [&](size_t bytes) -> void* {
        void* p = ws + off;
        off = (off + bytes + 255) & ~(size_t)255;
        return p;
    };
    int* row_ptr = (int*)alloc((NN + 1) * 4);
    int* cnt = (int*)alloc(NN * 4);
    int* cur = (int*)alloc(NN * 4);
    int* incl = (int*)alloc(NN * 4);
    int* part = (int*)alloc(64 * 4);
    int2* csr = (int2*)alloc((size_t)EE * 8);
    float2* scales = (float2*)alloc((size_t)NN * 8);
    float* query = (float*)alloc(BB * DD * 4);
    int* h0 = (int*)alloc(BB * 4);
    int* t_sel = (int*)alloc(BB * KK * 4);
    float* ssum = (float*)alloc(4);
    int* dflag = (int*)alloc(4);
    float* rel_emb = (float*)alloc((size_t)LL * RELSZ * 4);
    float* qe_f   = (float*)alloc((size_t)2 * RR * DD * 4);
    float* relW_f = (float*)alloc((size_t)LL * DD * 2 * RR * DD * 4);
    float* relb_f = (float*)alloc((size_t)LL * 2 * RR * DD * 4);
    float* linW_f = (float*)alloc((size_t)LL * XDIM * DD * 4);
    float* linb_f = (float*)alloc((size_t)LL * DD * 4);
    float* Wre    = (float*)alloc((size_t)LL * XDIM * DD * 4);
    float* w1_f   = (float*)alloc(4 * DD * DD * 4);
    float* b1_f   = (float*)alloc(2 * DD * 4);
    float* w2_f   = (float*)alloc(2 * DD * 4);
    float* b2_f   = (float*)alloc(4);
    u16* hid0 = (u16*)alloc((size_t)NN * BD * 2);
    u16* hid1 = (u16*)alloc((size_t)NN * BD * 2);

    hipMemsetAsync(cnt, 0, NN * 4, stream);
    hipMemsetAsync(cur, 0, NN * 4, stream);
    hipMemsetAsync(ssum, 0, 4, stream);
    // hid0 never read by layer 0 (select fast path) — no memset needed

    k_detect<<<1, 64, 0, stream>>>(d_in[4], dflag);
    auto conv = [&](int idx, float* dst, int n) {
        k_conv<<<(n + 255) / 256, 256, 0, stream>>>(d_in[idx], dst, n, dflag);
    };
    conv(4, qe_f, 2 * RR * DD);
    conv(5, relW_f, LL * DD * 2 * RR * DD);
    conv(6, relb_f, LL * 2 * RR * DD);
    conv(7, linW_f, LL * XDIM * DD);
    conv(8, linb_f, LL * DD);
    conv(9, w1_f, 4 * DD * DD);
    conv(10, b1_f, 2 * DD);
    conv(11, w2_f, 2 * DD);
    conv(12, b2_f, 1);
    k_reorg<<<(LL * XDIM * DD + 255) / 256, 256, 0, stream>>>(linW_f, Wre);

    k_degree<<<(EE + 255) / 256, 256, 0, stream>>>(el, cnt);
    int nb = (NN + SCAN_B - 1) / SCAN_B;
    k_scan1<<<nb, SCAN_B, 0, stream>>>(cnt, incl, part);
    k_scan2<<<1, 64, 0, stream>>>(part, nb);
    k_scan3<<<(NN + 255) / 256, 256, 0, stream>>>(incl, part, row_ptr);
    k_scatter<<<(EE + 255) / 256, 256, 0, stream>>>(el, row_ptr, cur, csr);
    k_scale_sum<<<(NN + 255) / 256, 256, 0, stream>>>(cnt, ssum);
    k_scale_fin<<<(NN + 255) / 256, 256, 0, stream>>>(cnt, ssum, scales);
    k_prep<<<1, 128, 0, stream>>>(h_index, t_index, r_index, qe_f, h0, t_sel, query);
    k_rel_emb_all<<<(LL * RELSZ + 255) / 256, 256, 0, stream>>>(query, relW_f, relb_f, rel_emb);

    u16* hin = hid0;
    u16* hout = hid1;
    for (int l = 0; l < LL; l++) {
        k_fused<<<NN / FB, 512, 0, stream>>>(
            row_ptr, csr, scales, query, h0, rel_emb + (size_t)l * RELSZ, hin, hout,
            Wre + (size_t)l * XDIM * DD, linb_f + l * DD, (l == 0) ? 1 : 0);
        u16* tmp = hin; hin = hout; hout = tmp;
    }
    k_score<<<BB * KK, 2 * DD, 0, stream>>>(hin, query, t_sel, w1_f, b1_f, w2_f, b2_f,
                                            d_out, dflag);
}

// Round 22
// 988.813 us; speedup vs baseline: 1.0062x; 1.0062x over previous
//
#include <hip/hip_runtime.h>
#include <hip/hip_bf16.h>

#define NN 50000
#define EE 500000
#define RR 100
#define DD 32
#define LL 6
#define BB 4
#define KK 33
#define BD 128      // B*D
#define XDIM 416    // 13*D
#define NROWS (NN * BB)
#define FEPS 1e-6f
#define SCAN_B 1024
#define FB 16       // nodes per fused block (50000 = 3125 * 16)
#define FR 64       // rows per fused block
#define FSTR 132    // LDS row stride (128 + 4 pad)
#define RELSZ (2 * RR * BB * DD)

typedef __hip_bfloat16 bf16;
typedef unsigned short u16;
typedef __attribute__((ext_vector_type(2))) float f32x2;

__device__ __forceinline__ float b2f(bf16 x) { return __bfloat162float(x); }
__device__ __forceinline__ float bfu2f(u16 u) { return __uint_as_float((unsigned)u << 16); }
__device__ __forceinline__ u16 f2bfu(float f) {   // RNE
    unsigned u = __float_as_uint(f);
    return (u16)((u + 0x7FFFu + ((u >> 16) & 1u)) >> 16);
}
__device__ __forceinline__ float4 bf4(ushort4 u) {
    return make_float4(bfu2f(u.x), bfu2f(u.y), bfu2f(u.z), bfu2f(u.w));
}

// ---------- input dtype detection ----------
__global__ void k_detect(const void* q, int* flag) {
    if (threadIdx.x == 0 && blockIdx.x == 0) {
        const unsigned short* u = (const unsigned short*)q;
        int wild = 0;
        for (int i = 0; i < 256; i++) {
            int expo = (u[i] >> 7) & 0xFF;
            if (expo >= 134) wild++;   // |bf16| >= 128 (incl inf/nan)
        }
        *flag = (wild > 8) ? 1 : 0;
    }
}

__global__ void k_conv(const void* __restrict__ src, float* __restrict__ dst, int n,
                       const int* __restrict__ flag) {
    int i = blockIdx.x * 256 + threadIdx.x;
    if (i < n) {
        if (*flag) dst[i] = ((const float*)src)[i];
        else       dst[i] = b2f(((const bf16*)src)[i]);
    }
}

// ---------- graph preprocessing ----------
__global__ void k_degree(const int* __restrict__ el, int* __restrict__ cnt) {
    int e = blockIdx.x * blockDim.x + threadIdx.x;
    if (e < EE) atomicAdd(&cnt[el[e * 3 + 1]], 1);
}

__global__ void k_scan1(const int* __restrict__ cnt, int* __restrict__ incl, int* __restrict__ part) {
    __shared__ int sd[SCAN_B];
    int tid = threadIdx.x;
    int i = blockIdx.x * SCAN_B + tid;
    int v = (i < NN) ? cnt[i] : 0;
    sd[tid] = v;
    __syncthreads();
    for (int off = 1; off < SCAN_B; off <<= 1) {
        int t = (tid >= off) ? sd[tid - off] : 0;
        __syncthreads();
        sd[tid] += t;
        __syncthreads();
    }
    if (i < NN) incl[i] = sd[tid];
    if (tid == SCAN_B - 1) part[blockIdx.x] = sd[tid];
}

__global__ void k_scan2(int* part, int nb) {
    if (threadIdx.x == 0 && blockIdx.x == 0) {
        int run = 0;
        for (int i = 0; i < nb; i++) { int t = part[i]; part[i] = run; run += t; }
    }
}

__global__ void k_scan3(const int* __restrict__ incl, const int* __restrict__ part, int* __restrict__ row_ptr) {
    int i = blockIdx.x * blockDim.x + threadIdx.x;
    if (i < NN) row_ptr[i + 1] = incl[i] + part[i / SCAN_B];
    if (i == 0) row_ptr[0] = 0;
}

__global__ void k_scatter(const int* __restrict__ el, const int* __restrict__ row_ptr,
                          int* __restrict__ cur, int2* __restrict__ csr) {
    int e = blockIdx.x * blockDim.x + threadIdx.x;
    if (e < EE) {
        int dst = el[e * 3 + 1];
        int pos = row_ptr[dst] + atomicAdd(&cur[dst], 1);
        csr[pos] = make_int2(el[e * 3 + 0], el[e * 3 + 2]);
    }
}

__global__ void k_scale_sum(const int* __restrict__ cnt, float* __restrict__ ssum) {
    __shared__ float sd[256];
    int i = blockIdx.x * 256 + threadIdx.x;
    float v = (i < NN) ? logf((float)(cnt[i] + 1)) : 0.f;
    sd[threadIdx.x] = v;
    __syncthreads();
    for (int off = 128; off; off >>= 1) {
        if (threadIdx.x < off) sd[threadIdx.x] += sd[threadIdx.x + off];
        __syncthreads();
    }
    if (threadIdx.x == 0) atomicAdd(ssum, sd[0]);
}

__global__ void k_scale_fin(const int* __restrict__ cnt, const float* __restrict__ ssum,
                            float2* __restrict__ scales) {
    int i = blockIdx.x * 256 + threadIdx.x;
    if (i < NN) {
        float mean = *ssum / (float)NN;
        float s = logf((float)(cnt[i] + 1)) / mean;
        scales[i] = make_float2(s, 1.f / fmaxf(s, 0.01f));
    }
}

// ---------- query prep ----------
__global__ void k_prep(const int* __restrict__ h_index, const int* __restrict__ t_index,
                       const int* __restrict__ r_index, const float* __restrict__ query_emb,
                       int* __restrict__ h0, int* __restrict__ t_sel,
                       float* __restrict__ query) {
    __shared__ int s_h0[BB], s_r0[BB], s_neg[BB];
    int tid = threadIdx.x;
    if (tid < BB) {
        int h00 = h_index[tid * KK];
        int alleq = 1;
        for (int k = 1; k < KK; k++) alleq &= (h_index[tid * KK + k] == h00) ? 1 : 0;
        s_neg[tid] = alleq;
        s_h0[tid] = alleq ? h00 : t_index[tid * KK];
        s_r0[tid] = alleq ? r_index[tid * KK] : r_index[tid * KK] + RR;
        h0[tid] = s_h0[tid];
    }
    __syncthreads();
    for (int i = tid; i < BB * KK; i += blockDim.x) {
        int b = i / KK;
        t_sel[i] = s_neg[b] ? t_index[i] : h_index[i];
    }
    for (int i = tid; i < BB * DD; i += blockDim.x) {
        int b = i / DD, d = i - b * DD;
        query[i] = query_emb[s_r0[b] * DD + d];
    }
}

// ---------- rel_emb for ALL layers in one launch ----------
__global__ void k_rel_emb_all(const float* __restrict__ query, const float* __restrict__ relW,
                              const float* __restrict__ relb, float* __restrict__ rel_emb) {
    int gi = blockIdx.x * 256 + threadIdx.x;   // over LL * 2R*B*D
    if (gi >= LL * RELSZ) return;
    int l = gi / RELSZ;
    int i = gi - l * RELSZ;
    int r = i / BD;
    int bd = i - r * BD;
    int b = bd >> 5, d = bd & 31;
    const float* relWl = relW + (size_t)l * DD * 2 * RR * DD;
    const float* relbl = relb + (size_t)l * 2 * RR * DD;
    float acc = relbl[r * DD + d];
    #pragma unroll 8
    for (int k = 0; k < DD; k++)
        acc += query[b * DD + k] * relWl[k * (2 * RR * DD) + r * DD + d];
    rel_emb[gi] = acc;
}

// Reorganize lin_W into [V (384 rows = k*3+p) | Wh (32 rows)] x 32 cols per layer.
__global__ void k_reorg(const float* __restrict__ linWf, float* __restrict__ Wre) {
    int i = blockIdx.x * 256 + threadIdx.x;
    if (i >= LL * XDIM * DD) return;
    int l = i / (XDIM * DD);
    int rem = i - l * (XDIM * DD);
    int r = rem >> 5, c = rem & 31;
    int src;
    if (r < 384) {
        int k = r / 3, p = r - k * 3;
        int d = k & 31, s = k >> 5;
        src = 32 + d * 12 + s * 3 + p;
    } else {
        src = r - 384;
    }
    Wre[i] = linWf[(size_t)l * XDIM * DD + src * 32 + c];
}

#define EDGE_ACC(h4, r4)                                                          \
    {                                                                             \
        float v0 = h4.x * r4.x, v1 = h4.y * r4.y, v2 = h4.z * r4.z, v3 = h4.w * r4.w; \
        s0 += v0; s1 += v1; s2 += v2; s3 += v3;                                   \
        q0 += v0 * v0; q1 += v1 * v1; q2 += v2 * v2; q3 += v3 * v3;               \
        mx0 = fmaxf(mx0, v0); mx1 = fmaxf(mx1, v1); mx2 = fmaxf(mx2, v2); mx3 = fmaxf(mx3, v3); \
        mn0 = fminf(mn0, v0); mn1 = fminf(mn1, v1); mn2 = fminf(mn2, v2); mn3 = fminf(mn3, v3); \
    }

// Fused layer: hidden stored in bf16 (compute fp32). 16 nodes / 512 threads.
// Phase A: gather (8B ushort4 loads, x4 unroll) -> stats -> LDS.
// Phase B: k-loop with f32x2 __builtin_elementwise_fma (compiler emits
//          v_pk_fma_f32 with free s_load scheduling; per-lane IEEE FMA in
//          identical order -> bit-identical to scalar). W SGPR-resident.
__global__ __launch_bounds__(512, 8) void k_fused(
    const int* __restrict__ row_ptr, const int2* __restrict__ csr,
    const float2* __restrict__ scales, const float* __restrict__ query,
    const int* __restrict__ h0v, const float* __restrict__ rel_emb,
    const u16* __restrict__ hin, u16* __restrict__ hout,
    const float* __restrict__ Wre, const float* __restrict__ lbl, int l0) {
    __shared__ float sx[FR * FSTR];
    int tid = threadIdx.x;
    int nb0 = blockIdx.x * FB;
    const float4 zf4 = make_float4(0.f, 0.f, 0.f, 0.f);

    // ---- Phase A: stats into LDS (one round, 16 node-groups) ----
    {
        int ni = tid >> 5;
        int n = nb0 + ni;
        int t = tid & 31;
        int b = t >> 3;
        int dq = t & 7;
        int boff = b * DD + dq * 4;
        int h0b = h0v[b];
        float4 qv = *(const float4*)&query[boff];

        float4 bv = (h0b == n) ? qv : zf4;
        float s0 = bv.x, s1 = bv.y, s2 = bv.z, s3 = bv.w;
        float q0 = bv.x * bv.x, q1 = bv.y * bv.y, q2 = bv.z * bv.z, q3 = bv.w * bv.w;
        float mx0 = bv.x, mx1 = bv.y, mx2 = bv.z, mx3 = bv.w;
        float mn0 = bv.x, mn1 = bv.y, mn2 = bv.z, mn3 = bv.w;

        int e0 = row_ptr[n], e1 = row_ptr[n + 1];
        int e = e0;
        if (l0) {
            for (; e + 2 <= e1; e += 2) {
                int2 sa = csr[e];
                int2 sb = csr[e + 1];
                float4 ra = *(const float4*)&rel_emb[(size_t)sa.y * BD + boff];
                float4 rb = *(const float4*)&rel_emb[(size_t)sb.y * BD + boff];
                float4 ha = (sa.x == h0b) ? qv : zf4;
                float4 hb = (sb.x == h0b) ? qv : zf4;
                EDGE_ACC(ha, ra);
                EDGE_ACC(hb, rb);
            }
            if (e < e1) {
                int2 sr = csr[e];
                float4 r4 = *(const float4*)&rel_emb[(size_t)sr.y * BD + boff];
                float4 h4 = (sr.x == h0b) ? qv : zf4;
                EDGE_ACC(h4, r4);
            }
        } else {
            for (; e + 4 <= e1; e += 4) {
                int2 sa = csr[e];
                int2 sb = csr[e + 1];
                int2 sc2 = csr[e + 2];
                int2 sd2 = csr[e + 3];
                ushort4 hau = *(const ushort4*)&hin[(size_t)sa.x * BD + boff];
                float4 ra = *(const float4*)&rel_emb[(size_t)sa.y * BD + boff];
                ushort4 hbu = *(const ushort4*)&hin[(size_t)sb.x * BD + boff];
                float4 rb = *(const float4*)&rel_emb[(size_t)sb.y * BD + boff];
                ushort4 hcu = *(const ushort4*)&hin[(size_t)sc2.x * BD + boff];
                float4 rc = *(const float4*)&rel_emb[(size_t)sc2.y * BD + boff];
                ushort4 hdu = *(const ushort4*)&hin[(size_t)sd2.x * BD + boff];
                float4 rd = *(const float4*)&rel_emb[(size_t)sd2.y * BD + boff];
                float4 ha = bf4(hau), hb = bf4(hbu), hc = bf4(hcu), hd = bf4(hdu);
                EDGE_ACC(ha, ra);
                EDGE_ACC(hb, rb);
                EDGE_ACC(hc, rc);
                EDGE_ACC(hd, rd);
            }
            for (; e + 2 <= e1; e += 2) {
                int2 sa = csr[e];
                int2 sb = csr[e + 1];
                ushort4 hau = *(const ushort4*)&hin[(size_t)sa.x * BD + boff];
                float4 ra = *(const float4*)&rel_emb[(size_t)sa.y * BD + boff];
                ushort4 hbu = *(const ushort4*)&hin[(size_t)sb.x * BD + boff];
                float4 rb = *(const float4*)&rel_emb[(size_t)sb.y * BD + boff];
                float4 ha = bf4(hau), hb = bf4(hbu);
                EDGE_ACC(ha, ra);
                EDGE_ACC(hb, rb);
            }
            if (e < e1) {
                int2 sr = csr[e];
                ushort4 hu = *(const ushort4*)&hin[(size_t)sr.x * BD + boff];
                float4 r4 = *(const float4*)&rel_emb[(size_t)sr.y * BD + boff];
                float4 h4 = bf4(hu);
                EDGE_ACC(h4, r4);
            }
        }
        float cinv = 1.f / (float)(e1 - e0 + 1);
        float me0 = s0 * cinv, me1 = s1 * cinv, me2 = s2 * cinv, me3 = s3 * cinv;
        float sd0 = sqrtf(fmaxf(q0 * cinv - me0 * me0, FEPS));
        float sd1 = sqrtf(fmaxf(q1 * cinv - me1 * me1, FEPS));
        float sd2 = sqrtf(fmaxf(q2 * cinv - me2 * me2, FEPS));
        float sd3 = sqrtf(fmaxf(q3 * cinv - me3 * me3, FEPS));

        int d0 = dq * 4;
        float* dst = &sx[(ni * BB + b) * FSTR];
        *(float4*)&dst[0 * 32 + d0] = make_float4(me0, me1, me2, me3);
        *(float4*)&dst[1 * 32 + d0] = make_float4(mx0, mx1, mx2, mx3);
        *(float4*)&dst[2 * 32 + d0] = make_float4(mn0, mn1, mn2, mn3);
        *(float4*)&dst[3 * 32 + d0] = make_float4(sd0, sd1, sd2, sd3);
    }
    __syncthreads();

    // ---- Phase B: matvec (8 waves x 4 cols each), f32x2 packed FMA ----
    int lr = tid & (FR - 1);
    int c0 = __builtin_amdgcn_readfirstlane((tid >> 6) << 2);  // wave-uniform col base
    int grow = blockIdx.x * FR + lr;
    float2 sc = scales[grow >> 2];
    const float* __restrict__ Wv = Wre;            // 384*32
    const float* __restrict__ Wh = Wre + 384 * 32;

    f32x2 A00 = {lbl[c0 + 0], lbl[c0 + 1]};
    f32x2 A01 = {lbl[c0 + 2], lbl[c0 + 3]};
    f32x2 A10 = {0.f, 0.f}, A11 = {0.f, 0.f};
    f32x2 A20 = {0.f, 0.f}, A21 = {0.f, 0.f};

    const float* xr = &sx[lr * FSTR];
    #pragma unroll 2
    for (int k4 = 0; k4 < 128; k4 += 4) {
        float4 x4 = *(const float4*)&xr[k4];   // ds_read_b128, conflict-free
        float xs[4] = {x4.x, x4.y, x4.z, x4.w};
        #pragma unroll
        for (int j = 0; j < 4; j++) {
            float x = xs[j];
            f32x2 xx = {x, x};
            const float* w = &Wv[(size_t)(k4 + j) * 96 + c0];
            f32x2 w00 = *(const f32x2*)&w[0];
            f32x2 w01 = *(const f32x2*)&w[2];
            f32x2 w10 = *(const f32x2*)&w[32];
            f32x2 w11 = *(const f32x2*)&w[34];
            f32x2 w20 = *(const f32x2*)&w[64];
            f32x2 w21 = *(const f32x2*)&w[66];
            A00 = __builtin_elementwise_fma(xx, w00, A00);
            A01 = __builtin_elementwise_fma(xx, w01, A01);
            A10 = __builtin_elementwise_fma(xx, w10, A10);
            A11 = __builtin_elementwise_fma(xx, w11, A11);
            A20 = __builtin_elementwise_fma(xx, w20, A20);
            A21 = __builtin_elementwise_fma(xx, w21, A21);
        }
    }
    float a0[4] = {A00[0], A00[1], A01[0], A01[1]};
    float a1[4] = {A10[0], A10[1], A11[0], A11[1]};
    float a2[4] = {A20[0], A20[1], A21[0], A21[1]};

    // hself: k2 ascending 0..31 (scalar, unchanged)
    if (l0) {
        int nB = grow >> 2, bB = grow & 3;
        bool selfq = (h0v[bB] == nB);
        const float* qrow = &query[bB * DD];
        #pragma unroll
        for (int q = 0; q < 8; q++) {
            float4 h4 = selfq ? *(const float4*)&qrow[q * 4] : zf4;
            float hx[4] = {h4.x, h4.y, h4.z, h4.w};
            #pragma unroll
            for (int j = 0; j < 4; j++) {
                const float* wh = &Wh[(size_t)(q * 4 + j) * 32 + c0];
                float x = hx[j];
                #pragma unroll
                for (int c = 0; c < 4; c++) a0[c] = fmaf(x, wh[c], a0[c]);
            }
        }
    } else {
        const unsigned* hrow32 = (const unsigned*)&hin[(size_t)grow * 32];
        #pragma unroll
        for (int q4 = 0; q4 < 4; q4++) {
            uint4 r4 = *(const uint4*)&hrow32[q4 * 4];
            unsigned uu[4] = {r4.x, r4.y, r4.z, r4.w};
            #pragma unroll
            for (int m = 0; m < 4; m++) {
                float xlo = __uint_as_float(uu[m] << 16);
                float xhi = __uint_as_float(uu[m] & 0xFFFF0000u);
                int kb = q4 * 8 + m * 2;
                const float* whl = &Wh[(size_t)kb * 32 + c0];
                const float* whh = &Wh[(size_t)(kb + 1) * 32 + c0];
                #pragma unroll
                for (int c = 0; c < 4; c++) a0[c] = fmaf(xlo, whl[c], a0[c]);
                #pragma unroll
                for (int c = 0; c < 4; c++) a0[c] = fmaf(xhi, whh[c], a0[c]);
            }
        }
    }

    float4 y;
    y.x = fmaxf(a0[0] + sc.x * a1[0] + sc.y * a2[0], 0.f);
    y.y = fmaxf(a0[1] + sc.x * a1[1] + sc.y * a2[1], 0.f);
    y.z = fmaxf(a0[2] + sc.x * a1[2] + sc.y * a2[2], 0.f);
    y.w = fmaxf(a0[3] + sc.x * a1[3] + sc.y * a2[3], 0.f);
    ushort4 yo;
    yo.x = f2bfu(y.x); yo.y = f2bfu(y.y); yo.z = f2bfu(y.z); yo.w = f2bfu(y.w);
    *(ushort4*)&hout[(size_t)grow * 32 + c0] = yo;
}

// ---------- scoring ----------
__global__ void k_score(const u16* __restrict__ hidden, const float* __restrict__ query,
                        const int* __restrict__ t_sel,
                        const float* __restrict__ W1, const float* __restrict__ b1,
                        const float* __restrict__ W2, const float* __restrict__ b2v,
                        void* __restrict__ out, const int* __restrict__ flag) {
    int bk = blockIdx.x;
    int b = bk / KK;
    int j = threadIdx.x;  // 0..63
    int t = t_sel[bk];
    __shared__ float feat[2 * DD];
    feat[j] = (j < DD) ? bfu2f(hidden[(size_t)t * BD + b * DD + j]) : query[b * DD + (j - DD)];
    __syncthreads();
    float acc = b1[j];
    #pragma unroll 8
    for (int i = 0; i < 2 * DD; i++) acc += feat[i] * W1[i * 2 * DD + j];
    float h = fmaxf(acc, 0.f);
    float c = h * W2[j];
    for (int off = 32; off; off >>= 1) c += __shfl_down(c, off);
    if (j == 0) {
        float r = c + b2v[0];
        if (*flag) ((float*)out)[bk] = r;
        else       ((bf16*)out)[bk] = __float2bfloat16(r);
    }
}

extern "C" void kernel_launch(void* const* d_in, const int* in_sizes, int n_in,
                              void* d_out, int out_size, void* d_ws, size_t ws_size,
                              hipStream_t stream) {
    const int* el = (const int*)d_in[0];
    const int* h_index = (const int*)d_in[1];
    const int* t_index = (const int*)d_in[2];
    const int* r_index = (const int*)d_in[3];

    char* ws = (char*)d_ws;
    size_t off = 0;
    auto alloc = [&](size_t bytes) -> void* {
        void* p = ws + off;
        off = (off + bytes + 255) & ~(size_t)255;
        return p;
    };
    int* row_ptr = (int*)alloc((NN + 1) * 4);
    int* cnt = (int*)alloc(NN * 4);
    int* cur = (int*)alloc(NN * 4);
    int* incl = (int*)alloc(NN * 4);
    int* part = (int*)alloc(64 * 4);
    int2* csr = (int2*)alloc((size_t)EE * 8);
    float2* scales = (float2*)alloc((size_t)NN * 8);
    float* query = (float*)alloc(BB * DD * 4);
    int* h0 = (int*)alloc(BB * 4);
    int* t_sel = (int*)alloc(BB * KK * 4);
    float* ssum = (float*)alloc(4);
    int* dflag = (int*)alloc(4);
    float* rel_emb = (float*)alloc((size_t)LL * RELSZ * 4);
    float* qe_f   = (float*)alloc((size_t)2 * RR * DD * 4);
    float* relW_f = (float*)alloc((size_t)LL * DD * 2 * RR * DD * 4);
    float* relb_f = (float*)alloc((size_t)LL * 2 * RR * DD * 4);
    float* linW_f = (float*)alloc((size_t)LL * XDIM * DD * 4);
    float* linb_f = (float*)alloc((size_t)LL * DD * 4);
    float* Wre    = (float*)alloc((size_t)LL * XDIM * DD * 4);
    float* w1_f   = (float*)alloc(4 * DD * DD * 4);
    float* b1_f   = (float*)alloc(2 * DD * 4);
    float* w2_f   = (float*)alloc(2 * DD * 4);
    float* b2_f   = (float*)alloc(4);
    u16* hid0 = (u16*)alloc((size_t)NN * BD * 2);
    u16* hid1 = (u16*)alloc((size_t)NN * BD * 2);

    hipMemsetAsync(cnt, 0, NN * 4, stream);
    hipMemsetAsync(cur, 0, NN * 4, stream);
    hipMemsetAsync(ssum, 0, 4, stream);
    // hid0 never read by layer 0 (select fast path) — no memset needed

    k_detect<<<1, 64, 0, stream>>>(d_in[4], dflag);
    auto conv = [&](int idx, float* dst, int n) {
        k_conv<<<(n + 255) / 256, 256, 0, stream>>>(d_in[idx], dst, n, dflag);
    };
    conv(4, qe_f, 2 * RR * DD);
    conv(5, relW_f, LL * DD * 2 * RR * DD);
    conv(6, relb_f, LL * 2 * RR * DD);
    conv(7, linW_f, LL * XDIM * DD);
    conv(8, linb_f, LL * DD);
    conv(9, w1_f, 4 * DD * DD);
    conv(10, b1_f, 2 * DD);
    conv(11, w2_f, 2 * DD);
    conv(12, b2_f, 1);
    k_reorg<<<(LL * XDIM * DD + 255) / 256, 256, 0, stream>>>(linW_f, Wre);

    k_degree<<<(EE + 255) / 256, 256, 0, stream>>>(el, cnt);
    int nb = (NN + SCAN_B - 1) / SCAN_B;
    k_scan1<<<nb, SCAN_B, 0, stream>>>(cnt, incl, part);
    k_scan2<<<1, 64, 0, stream>>>(part, nb);
    k_scan3<<<(NN + 255) / 256, 256, 0, stream>>>(incl, part, row_ptr);
    k_scatter<<<(EE + 255) / 256, 256, 0, stream>>>(el, row_ptr, cur, csr);
    k_scale_sum<<<(NN + 255) / 256, 256, 0, stream>>>(cnt, ssum);
    k_scale_fin<<<(NN + 255) / 256, 256, 0, stream>>>(cnt, ssum, scales);
    k_prep<<<1, 128, 0, stream>>>(h_index, t_index, r_index, qe_f, h0, t_sel, query);
    k_rel_emb_all<<<(LL * RELSZ + 255) / 256, 256, 0, stream>>>(query, relW_f, relb_f, rel_emb);

    u16* hin = hid0;
    u16* hout = hid1;
    for (int l = 0; l < LL; l++) {
        k_fused<<<NN / FB, 512, 0, stream>>>(
            row_ptr, csr, scales, query, h0, rel_emb + (size_t)l * RELSZ, hin, hout,
            Wre + (size_t)l * XDIM * DD, linb_f + l * DD, (l == 0) ? 1 : 0);
        u16* tmp = hin; hin = hout; hout = tmp;
    }
    k_score<<<BB * KK, 2 * DD, 0, stream>>>(hin, query, t_sel, w1_f, b1_f, w2_f, b2_f,
                                            d_out, dflag);
}

// Round 23
// 699.574 us; speedup vs baseline: 1.4223x; 1.4135x over previous
//
#include <hip/hip_runtime.h>
#include <hip/hip_bf16.h>

#define NN 50000
#define EE 500000
#define RR 100
#define DD 32
#define LL 6
#define BB 4
#define KK 33
#define BD 128      // B*D
#define XDIM 416    // 13*D
#define NROWS (NN * BB)
#define FEPS 1e-6f
#define SCAN_B 1024
#define FB 16       // nodes per fused block (50000 = 3125 * 16)
#define FR 64       // rows per fused block
#define FSTR 132    // LDS row stride (128 + 4 pad)
#define RELSZ (2 * RR * BB * DD)

typedef __hip_bfloat16 bf16;
typedef unsigned short u16;

__device__ __forceinline__ float b2f(bf16 x) { return __bfloat162float(x); }
__device__ __forceinline__ float bfu2f(u16 u) { return __uint_as_float((unsigned)u << 16); }
__device__ __forceinline__ u16 f2bfu(float f) {   // RNE
    unsigned u = __float_as_uint(f);
    return (u16)((u + 0x7FFFu + ((u >> 16) & 1u)) >> 16);
}
__device__ __forceinline__ float4 bf4(ushort4 u) {
    return make_float4(bfu2f(u.x), bfu2f(u.y), bfu2f(u.z), bfu2f(u.w));
}

// ---------- input dtype detection ----------
__global__ void k_detect(const void* q, int* flag) {
    if (threadIdx.x == 0 && blockIdx.x == 0) {
        const unsigned short* u = (const unsigned short*)q;
        int wild = 0;
        for (int i = 0; i < 256; i++) {
            int expo = (u[i] >> 7) & 0xFF;
            if (expo >= 134) wild++;   // |bf16| >= 128 (incl inf/nan)
        }
        *flag = (wild > 8) ? 1 : 0;
    }
}

__global__ void k_conv(const void* __restrict__ src, float* __restrict__ dst, int n,
                       const int* __restrict__ flag) {
    int i = blockIdx.x * 256 + threadIdx.x;
    if (i < n) {
        if (*flag) dst[i] = ((const float*)src)[i];
        else       dst[i] = b2f(((const bf16*)src)[i]);
    }
}

// ---------- graph preprocessing ----------
__global__ void k_degree(const int* __restrict__ el, int* __restrict__ cnt) {
    int e = blockIdx.x * blockDim.x + threadIdx.x;
    if (e < EE) atomicAdd(&cnt[el[e * 3 + 1]], 1);
}

__global__ void k_scan1(const int* __restrict__ cnt, int* __restrict__ incl, int* __restrict__ part) {
    __shared__ int sd[SCAN_B];
    int tid = threadIdx.x;
    int i = blockIdx.x * SCAN_B + tid;
    int v = (i < NN) ? cnt[i] : 0;
    sd[tid] = v;
    __syncthreads();
    for (int off = 1; off < SCAN_B; off <<= 1) {
        int t = (tid >= off) ? sd[tid - off] : 0;
        __syncthreads();
        sd[tid] += t;
        __syncthreads();
    }
    if (i < NN) incl[i] = sd[tid];
    if (tid == SCAN_B - 1) part[blockIdx.x] = sd[tid];
}

__global__ void k_scan2(int* part, int nb) {
    if (threadIdx.x == 0 && blockIdx.x == 0) {
        int run = 0;
        for (int i = 0; i < nb; i++) { int t = part[i]; part[i] = run; run += t; }
    }
}

__global__ void k_scan3(const int* __restrict__ incl, const int* __restrict__ part, int* __restrict__ row_ptr) {
    int i = blockIdx.x * blockDim.x + threadIdx.x;
    if (i < NN) row_ptr[i + 1] = incl[i] + part[i / SCAN_B];
    if (i == 0) row_ptr[0] = 0;
}

__global__ void k_scatter(const int* __restrict__ el, const int* __restrict__ row_ptr,
                          int* __restrict__ cur, int2* __restrict__ csr) {
    int e = blockIdx.x * blockDim.x + threadIdx.x;
    if (e < EE) {
        int dst = el[e * 3 + 1];
        int pos = row_ptr[dst] + atomicAdd(&cur[dst], 1);
        csr[pos] = make_int2(el[e * 3 + 0], el[e * 3 + 2]);
    }
}

__global__ void k_scale_sum(const int* __restrict__ cnt, float* __restrict__ ssum) {
    __shared__ float sd[256];
    int i = blockIdx.x * 256 + threadIdx.x;
    float v = (i < NN) ? logf((float)(cnt[i] + 1)) : 0.f;
    sd[threadIdx.x] = v;
    __syncthreads();
    for (int off = 128; off; off >>= 1) {
        if (threadIdx.x < off) sd[threadIdx.x] += sd[threadIdx.x + off];
        __syncthreads();
    }
    if (threadIdx.x == 0) atomicAdd(ssum, sd[0]);
}

__global__ void k_scale_fin(const int* __restrict__ cnt, const float* __restrict__ ssum,
                            float2* __restrict__ scales) {
    int i = blockIdx.x * 256 + threadIdx.x;
    if (i < NN) {
        float mean = *ssum / (float)NN;
        float s = logf((float)(cnt[i] + 1)) / mean;
        scales[i] = make_float2(s, 1.f / fmaxf(s, 0.01f));
    }
}

// ---------- query prep ----------
__global__ void k_prep(const int* __restrict__ h_index, const int* __restrict__ t_index,
                       const int* __restrict__ r_index, const float* __restrict__ query_emb,
                       int* __restrict__ h0, int* __restrict__ t_sel,
                       float* __restrict__ query) {
    __shared__ int s_h0[BB], s_r0[BB], s_neg[BB];
    int tid = threadIdx.x;
    if (tid < BB) {
        int h00 = h_index[tid * KK];
        int alleq = 1;
        for (int k = 1; k < KK; k++) alleq &= (h_index[tid * KK + k] == h00) ? 1 : 0;
        s_neg[tid] = alleq;
        s_h0[tid] = alleq ? h00 : t_index[tid * KK];
        s_r0[tid] = alleq ? r_index[tid * KK] : r_index[tid * KK] + RR;
        h0[tid] = s_h0[tid];
    }
    __syncthreads();
    for (int i = tid; i < BB * KK; i += blockDim.x) {
        int b = i / KK;
        t_sel[i] = s_neg[b] ? t_index[i] : h_index[i];
    }
    for (int i = tid; i < BB * DD; i += blockDim.x) {
        int b = i / DD, d = i - b * DD;
        query[i] = query_emb[s_r0[b] * DD + d];
    }
}

// ---------- rel_emb for ALL layers in one launch ----------
__global__ void k_rel_emb_all(const float* __restrict__ query, const float* __restrict__ relW,
                              const float* __restrict__ relb, float* __restrict__ rel_emb) {
    int gi = blockIdx.x * 256 + threadIdx.x;   // over LL * 2R*B*D
    if (gi >= LL * RELSZ) return;
    int l = gi / RELSZ;
    int i = gi - l * RELSZ;
    int r = i / BD;
    int bd = i - r * BD;
    int b = bd >> 5, d = bd & 31;
    const float* relWl = relW + (size_t)l * DD * 2 * RR * DD;
    const float* relbl = relb + (size_t)l * 2 * RR * DD;
    float acc = relbl[r * DD + d];
    #pragma unroll 8
    for (int k = 0; k < DD; k++)
        acc += query[b * DD + k] * relWl[k * (2 * RR * DD) + r * DD + d];
    rel_emb[gi] = acc;
}

// Reorganize lin_W into [V (384 rows = k*3+p) | Wh (32 rows)] x 32 cols per layer.
__global__ void k_reorg(const float* __restrict__ linWf, float* __restrict__ Wre) {
    int i = blockIdx.x * 256 + threadIdx.x;
    if (i >= LL * XDIM * DD) return;
    int l = i / (XDIM * DD);
    int rem = i - l * (XDIM * DD);
    int r = rem >> 5, c = rem & 31;
    int src;
    if (r < 384) {
        int k = r / 3, p = r - k * 3;
        int d = k & 31, s = k >> 5;
        src = 32 + d * 12 + s * 3 + p;
    } else {
        src = r - 384;
    }
    Wre[i] = linWf[(size_t)l * XDIM * DD + src * 32 + c];
}

#define EDGE_ACC(h4, r4)                                                          \
    {                                                                             \
        float v0 = h4.x * r4.x, v1 = h4.y * r4.y, v2 = h4.z * r4.z, v3 = h4.w * r4.w; \
        s0 += v0; s1 += v1; s2 += v2; s3 += v3;                                   \
        q0 += v0 * v0; q1 += v1 * v1; q2 += v2 * v2; q3 += v3 * v3;               \
        mx0 = fmaxf(mx0, v0); mx1 = fmaxf(mx1, v1); mx2 = fmaxf(mx2, v2); mx3 = fmaxf(mx3, v3); \
        mn0 = fminf(mn0, v0); mn1 = fminf(mn1, v1); mn2 = fminf(mn2, v2); mn3 = fminf(mn3, v3); \
    }

// Fused layer: hidden stored in bf16 (compute fp32). 16 nodes / 512 threads.
// Phase A: gather (8B ushort4 loads, x4 unroll) -> stats -> LDS.
//   l0==1: hin row = (src==h0[b]) ? query : 0 (register select, exact fp32).
// Phase B: 3-accumulator matvec, W wave-uniform SGPR; bf16 out (RNE).
__global__ __launch_bounds__(512, 8) void k_fused(
    const int* __restrict__ row_ptr, const int2* __restrict__ csr,
    const float2* __restrict__ scales, const float* __restrict__ query,
    const int* __restrict__ h0v, const float* __restrict__ rel_emb,
    const u16* __restrict__ hin, u16* __restrict__ hout,
    const float* __restrict__ Wre, const float* __restrict__ lbl, int l0) {
    __shared__ float sx[FR * FSTR];
    int tid = threadIdx.x;
    int nb0 = blockIdx.x * FB;
    const float4 zf4 = make_float4(0.f, 0.f, 0.f, 0.f);

    // ---- Phase A: stats into LDS (one round, 16 node-groups) ----
    {
        int ni = tid >> 5;
        int n = nb0 + ni;
        int t = tid & 31;
        int b = t >> 3;
        int dq = t & 7;
        int boff = b * DD + dq * 4;
        int h0b = h0v[b];
        float4 qv = *(const float4*)&query[boff];

        float4 bv = (h0b == n) ? qv : zf4;
        float s0 = bv.x, s1 = bv.y, s2 = bv.z, s3 = bv.w;
        float q0 = bv.x * bv.x, q1 = bv.y * bv.y, q2 = bv.z * bv.z, q3 = bv.w * bv.w;
        float mx0 = bv.x, mx1 = bv.y, mx2 = bv.z, mx3 = bv.w;
        float mn0 = bv.x, mn1 = bv.y, mn2 = bv.z, mn3 = bv.w;

        int e0 = row_ptr[n], e1 = row_ptr[n + 1];
        int e = e0;
        if (l0) {
            for (; e + 2 <= e1; e += 2) {
                int2 sa = csr[e];
                int2 sb = csr[e + 1];
                float4 ra = *(const float4*)&rel_emb[(size_t)sa.y * BD + boff];
                float4 rb = *(const float4*)&rel_emb[(size_t)sb.y * BD + boff];
                float4 ha = (sa.x == h0b) ? qv : zf4;
                float4 hb = (sb.x == h0b) ? qv : zf4;
                EDGE_ACC(ha, ra);
                EDGE_ACC(hb, rb);
            }
            if (e < e1) {
                int2 sr = csr[e];
                float4 r4 = *(const float4*)&rel_emb[(size_t)sr.y * BD + boff];
                float4 h4 = (sr.x == h0b) ? qv : zf4;
                EDGE_ACC(h4, r4);
            }
        } else {
            for (; e + 4 <= e1; e += 4) {
                int2 sa = csr[e];
                int2 sb = csr[e + 1];
                int2 sc2 = csr[e + 2];
                int2 sd2 = csr[e + 3];
                ushort4 hau = *(const ushort4*)&hin[(size_t)sa.x * BD + boff];
                float4 ra = *(const float4*)&rel_emb[(size_t)sa.y * BD + boff];
                ushort4 hbu = *(const ushort4*)&hin[(size_t)sb.x * BD + boff];
                float4 rb = *(const float4*)&rel_emb[(size_t)sb.y * BD + boff];
                ushort4 hcu = *(const ushort4*)&hin[(size_t)sc2.x * BD + boff];
                float4 rc = *(const float4*)&rel_emb[(size_t)sc2.y * BD + boff];
                ushort4 hdu = *(const ushort4*)&hin[(size_t)sd2.x * BD + boff];
                float4 rd = *(const float4*)&rel_emb[(size_t)sd2.y * BD + boff];
                float4 ha = bf4(hau), hb = bf4(hbu), hc = bf4(hcu), hd = bf4(hdu);
                EDGE_ACC(ha, ra);
                EDGE_ACC(hb, rb);
                EDGE_ACC(hc, rc);
                EDGE_ACC(hd, rd);
            }
            for (; e + 2 <= e1; e += 2) {
                int2 sa = csr[e];
                int2 sb = csr[e + 1];
                ushort4 hau = *(const ushort4*)&hin[(size_t)sa.x * BD + boff];
                float4 ra = *(const float4*)&rel_emb[(size_t)sa.y * BD + boff];
                ushort4 hbu = *(const ushort4*)&hin[(size_t)sb.x * BD + boff];
                float4 rb = *(const float4*)&rel_emb[(size_t)sb.y * BD + boff];
                float4 ha = bf4(hau), hb = bf4(hbu);
                EDGE_ACC(ha, ra);
                EDGE_ACC(hb, rb);
            }
            if (e < e1) {
                int2 sr = csr[e];
                ushort4 hu = *(const ushort4*)&hin[(size_t)sr.x * BD + boff];
                float4 r4 = *(const float4*)&rel_emb[(size_t)sr.y * BD + boff];
                float4 h4 = bf4(hu);
                EDGE_ACC(h4, r4);
            }
        }
        float cinv = 1.f / (float)(e1 - e0 + 1);
        float me0 = s0 * cinv, me1 = s1 * cinv, me2 = s2 * cinv, me3 = s3 * cinv;
        float sd0 = sqrtf(fmaxf(q0 * cinv - me0 * me0, FEPS));
        float sd1 = sqrtf(fmaxf(q1 * cinv - me1 * me1, FEPS));
        float sd2 = sqrtf(fmaxf(q2 * cinv - me2 * me2, FEPS));
        float sd3 = sqrtf(fmaxf(q3 * cinv - me3 * me3, FEPS));

        int d0 = dq * 4;
        float* dst = &sx[(ni * BB + b) * FSTR];
        *(float4*)&dst[0 * 32 + d0] = make_float4(me0, me1, me2, me3);
        *(float4*)&dst[1 * 32 + d0] = make_float4(mx0, mx1, mx2, mx3);
        *(float4*)&dst[2 * 32 + d0] = make_float4(mn0, mn1, mn2, mn3);
        *(float4*)&dst[3 * 32 + d0] = make_float4(sd0, sd1, sd2, sd3);
    }
    __syncthreads();

    // ---- Phase B: matvec (8 waves x 4 cols each), 3 accumulators ----
    int lr = tid & (FR - 1);
    int c0 = __builtin_amdgcn_readfirstlane((tid >> 6) << 2);  // wave-uniform col base
    int grow = blockIdx.x * FR + lr;
    float2 sc = scales[grow >> 2];
    const float* __restrict__ Wv = Wre;            // 384*32
    const float* __restrict__ Wh = Wre + 384 * 32;

    float a0[4], a1[4], a2[4];
    #pragma unroll
    for (int c = 0; c < 4; c++) { a0[c] = lbl[c0 + c]; a1[c] = 0.f; a2[c] = 0.f; }

    const float* xr = &sx[lr * FSTR];
    #pragma unroll 4
    for (int k = 0; k < 128; k++) {
        float x = xr[k];
        const float* w = &Wv[(size_t)k * 96 + c0];
        #pragma unroll
        for (int c = 0; c < 4; c++) {
            a0[c] = fmaf(x, w[c], a0[c]);
            a1[c] = fmaf(x, w[32 + c], a1[c]);
            a2[c] = fmaf(x, w[64 + c], a2[c]);
        }
    }
    // hself: k2 ascending 0..31
    if (l0) {
        int nB = grow >> 2, bB = grow & 3;
        bool selfq = (h0v[bB] == nB);
        const float* qrow = &query[bB * DD];
        #pragma unroll
        for (int q = 0; q < 8; q++) {
            float4 h4 = selfq ? *(const float4*)&qrow[q * 4] : zf4;
            float hx[4] = {h4.x, h4.y, h4.z, h4.w};
            #pragma unroll
            for (int j = 0; j < 4; j++) {
                const float* wh = &Wh[(size_t)(q * 4 + j) * 32 + c0];
                float x = hx[j];
                #pragma unroll
                for (int c = 0; c < 4; c++) a0[c] = fmaf(x, wh[c], a0[c]);
            }
        }
    } else {
        const unsigned* hrow32 = (const unsigned*)&hin[(size_t)grow * 32];
        #pragma unroll
        for (int q4 = 0; q4 < 4; q4++) {
            uint4 r4 = *(const uint4*)&hrow32[q4 * 4];
            unsigned uu[4] = {r4.x, r4.y, r4.z, r4.w};
            #pragma unroll
            for (int m = 0; m < 4; m++) {
                float xlo = __uint_as_float(uu[m] << 16);
                float xhi = __uint_as_float(uu[m] & 0xFFFF0000u);
                int kb = q4 * 8 + m * 2;
                const float* whl = &Wh[(size_t)kb * 32 + c0];
                const float* whh = &Wh[(size_t)(kb + 1) * 32 + c0];
                #pragma unroll
                for (int c = 0; c < 4; c++) a0[c] = fmaf(xlo, whl[c], a0[c]);
                #pragma unroll
                for (int c = 0; c < 4; c++) a0[c] = fmaf(xhi, whh[c], a0[c]);
            }
        }
    }

    float4 y;
    y.x = fmaxf(a0[0] + sc.x * a1[0] + sc.y * a2[0], 0.f);
    y.y = fmaxf(a0[1] + sc.x * a1[1] + sc.y * a2[1], 0.f);
    y.z = fmaxf(a0[2] + sc.x * a1[2] + sc.y * a2[2], 0.f);
    y.w = fmaxf(a0[3] + sc.x * a1[3] + sc.y * a2[3], 0.f);
    ushort4 yo;
    yo.x = f2bfu(y.x); yo.y = f2bfu(y.y); yo.z = f2bfu(y.z); yo.w = f2bfu(y.w);
    *(ushort4*)&hout[(size_t)grow * 32 + c0] = yo;
}

// ---------- scoring ----------
__global__ void k_score(const u16* __restrict__ hidden, const float* __restrict__ query,
                        const int* __restrict__ t_sel,
                        const float* __restrict__ W1, const float* __restrict__ b1,
                        const float* __restrict__ W2, const float* __restrict__ b2v,
                        void* __restrict__ out, const int* __restrict__ flag) {
    int bk = blockIdx.x;
    int b = bk / KK;
    int j = threadIdx.x;  // 0..63
    int t = t_sel[bk];
    __shared__ float feat[2 * DD];
    feat[j] = (j < DD) ? bfu2f(hidden[(size_t)t * BD + b * DD + j]) : query[b * DD + (j - DD)];
    __syncthreads();
    float acc = b1[j];
    #pragma unroll 8
    for (int i = 0; i < 2 * DD; i++) acc += feat[i] * W1[i * 2 * DD + j];
    float h = fmaxf(acc, 0.f);
    float c = h * W2[j];
    for (int off = 32; off; off >>= 1) c += __shfl_down(c, off);
    if (j == 0) {
        float r = c + b2v[0];
        if (*flag) ((float*)out)[bk] = r;
        else       ((bf16*)out)[bk] = __float2bfloat16(r);
    }
}

extern "C" void kernel_launch(void* const* d_in, const int* in_sizes, int n_in,
                              void* d_out, int out_size, void* d_ws, size_t ws_size,
                              hipStream_t stream) {
    const int* el = (const int*)d_in[0];
    const int* h_index = (const int*)d_in[1];
    const int* t_index = (const int*)d_in[2];
    const int* r_index = (const int*)d_in[3];

    char* ws = (char*)d_ws;
    size_t off = 0;
    auto alloc = [&](size_t bytes) -> void* {
        void* p = ws + off;
        off = (off + bytes + 255) & ~(size_t)255;
        return p;
    };
    int* row_ptr = (int*)alloc((NN + 1) * 4);
    int* cnt = (int*)alloc(NN * 4);
    int* cur = (int*)alloc(NN * 4);
    int* incl = (int*)alloc(NN * 4);
    int* part = (int*)alloc(64 * 4);
    int2* csr = (int2*)alloc((size_t)EE * 8);
    float2* scales = (float2*)alloc((size_t)NN * 8);
    float* query = (float*)alloc(BB * DD * 4);
    int* h0 = (int*)alloc(BB * 4);
    int* t_sel = (int*)alloc(BB * KK * 4);
    float* ssum = (float*)alloc(4);
    int* dflag = (int*)alloc(4);
    float* rel_emb = (float*)alloc((size_t)LL * RELSZ * 4);
    float* qe_f   = (float*)alloc((size_t)2 * RR * DD * 4);
    float* relW_f = (float*)alloc((size_t)LL * DD * 2 * RR * DD * 4);
    float* relb_f = (float*)alloc((size_t)LL * 2 * RR * DD * 4);
    float* linW_f = (float*)alloc((size_t)LL * XDIM * DD * 4);
    float* linb_f = (float*)alloc((size_t)LL * DD * 4);
    float* Wre    = (float*)alloc((size_t)LL * XDIM * DD * 4);
    float* w1_f   = (float*)alloc(4 * DD * DD * 4);
    float* b1_f   = (float*)alloc(2 * DD * 4);
    float* w2_f   = (float*)alloc(2 * DD * 4);
    float* b2_f   = (float*)alloc(4);
    u16* hid0 = (u16*)alloc((size_t)NN * BD * 2);
    u16* hid1 = (u16*)alloc((size_t)NN * BD * 2);

    hipMemsetAsync(cnt, 0, NN * 4, stream);
    hipMemsetAsync(cur, 0, NN * 4, stream);
    hipMemsetAsync(ssum, 0, 4, stream);
    // hid0 never read by layer 0 (select fast path) — no memset needed

    k_detect<<<1, 64, 0, stream>>>(d_in[4], dflag);
    auto conv = [&](int idx, float* dst, int n) {
        k_conv<<<(n + 255) / 256, 256, 0, stream>>>(d_in[idx], dst, n, dflag);
    };
    conv(4, qe_f, 2 * RR * DD);
    conv(5, relW_f, LL * DD * 2 * RR * DD);
    conv(6, relb_f, LL * 2 * RR * DD);
    conv(7, linW_f, LL * XDIM * DD);
    conv(8, linb_f, LL * DD);
    conv(9, w1_f, 4 * DD * DD);
    conv(10, b1_f, 2 * DD);
    conv(11, w2_f, 2 * DD);
    conv(12, b2_f, 1);
    k_reorg<<<(LL * XDIM * DD + 255) / 256, 256, 0, stream>>>(linW_f, Wre);

    k_degree<<<(EE + 255) / 256, 256, 0, stream>>>(el, cnt);
    int nb = (NN + SCAN_B - 1) / SCAN_B;
    k_scan1<<<nb, SCAN_B, 0, stream>>>(cnt, incl, part);
    k_scan2<<<1, 64, 0, stream>>>(part, nb);
    k_scan3<<<(NN + 255) / 256, 256, 0, stream>>>(incl, part, row_ptr);
    k_scatter<<<(EE + 255) / 256, 256, 0, stream>>>(el, row_ptr, cur, csr);
    k_scale_sum<<<(NN + 255) / 256, 256, 0, stream>>>(cnt, ssum);
    k_scale_fin<<<(NN + 255) / 256, 256, 0, stream>>>(cnt, ssum, scales);
    k_prep<<<1, 128, 0, stream>>>(h_index, t_index, r_index, qe_f, h0, t_sel, query);
    k_rel_emb_all<<<(LL * RELSZ + 255) / 256, 256, 0, stream>>>(query, relW_f, relb_f, rel_emb);

    u16* hin = hid0;
    u16* hout = hid1;
    for (int l = 0; l < LL; l++) {
        k_fused<<<NN / FB, 512, 0, stream>>>(
            row_ptr, csr, scales, query, h0, rel_emb + (size_t)l * RELSZ, hin, hout,
            Wre + (size_t)l * XDIM * DD, linb_f + l * DD, (l == 0) ? 1 : 0);
        u16* tmp = hin; hin = hout; hout = tmp;
    }
    k_score<<<BB * KK, 2 * DD, 0, stream>>>(hin, query, t_sel, w1_f, b1_f, w2_f, b2_f,
                                            d_out, dflag);
}